// Round 17
// baseline (1530.226 us; speedup 1.0000x reference)
//
#include <hip/hip_runtime.h>
#include <hip/hip_bf16.h>

#define NF 1304
#define M1 652
#define M2 326
#define CH 32
#define NHEAD1 8
#define HID1 4
#define NLAYER 3
#define FRAG 50
#define NBATCH 8
#define DPAD 32   // degree counter padding (128B line per node)
#define QK 328    // K per quarter (q0..q2=328, q3=320); 328*4B % 16 == 0 (alignment)

static inline int ceil_div(int a, int b){ return (a + b - 1)/b; }

__device__ __forceinline__ unsigned short f2h(float f){
  _Float16 h = (_Float16)f;
  unsigned short u;
  __builtin_memcpy(&u, &h, 2);
  return u;
}
__device__ __forceinline__ float h2f(unsigned short u){
  _Float16 h;
  __builtin_memcpy(&h, &u, 2);
  return (float)h;
}

// ---------------- generic fp32 tiled GEMM (used only for tiny weight folds) ----
#define TM 64
#define TN 64
#define TKK 16
__global__ __launch_bounds__(256) void gemm_bias(
    const float* __restrict__ A, int lda,
    const float* __restrict__ B, int ldb,
    const float* __restrict__ bias,
    float* __restrict__ C, int ldc,
    int M, int N, int K, int acc)
{
  __shared__ float As[TKK][TM + 1];
  __shared__ float Bs[TKK][TN];
  int tid = threadIdx.x;
  int tx = tid & 15, ty = tid >> 4;
  int row0 = blockIdx.y * TM, col0 = blockIdx.x * TN;
  float c[4][4] = {};
  for (int k0 = 0; k0 < K; k0 += TKK) {
    #pragma unroll
    for (int p = 0; p < 4; ++p) {
      int r = (tid >> 4) + p * 16;
      int kk = tid & 15;
      int gr = row0 + r, gk = k0 + kk;
      float v = 0.f;
      if (gr < M && gk < K) v = A[(long long)gr * lda + gk];
      As[kk][r] = v;
    }
    #pragma unroll
    for (int p = 0; p < 4; ++p) {
      int kk = (tid >> 6) + p * 4;
      int cc = tid & 63;
      int gk = k0 + kk, gc = col0 + cc;
      float v = 0.f;
      if (gk < K && gc < N) v = B[(long long)gk * ldb + gc];
      Bs[kk][cc] = v;
    }
    __syncthreads();
    #pragma unroll
    for (int kk = 0; kk < TKK; ++kk) {
      float a[4], b[4];
      #pragma unroll
      for (int i = 0; i < 4; ++i) a[i] = As[kk][ty + 16 * i];
      #pragma unroll
      for (int j = 0; j < 4; ++j) b[j] = Bs[kk][tx + 16 * j];
      #pragma unroll
      for (int i = 0; i < 4; ++i)
        #pragma unroll
        for (int j = 0; j < 4; ++j)
          c[i][j] += a[i] * b[j];
    }
    __syncthreads();
  }
  #pragma unroll
  for (int i = 0; i < 4; ++i) {
    int gr = row0 + ty + 16 * i;
    if (gr >= M) continue;
    #pragma unroll
    for (int j = 0; j < 4; ++j) {
      int gc = col0 + tx + 16 * j;
      if (gc >= N) continue;
      float v = c[i][j];
      if (bias) v += bias[gc];
      if (acc) v += C[(long long)gr * ldc + gc];
      C[(long long)gr * ldc + gc] = v;
    }
  }
}

// ---- fold misc: Wbig[0:24,:] = Wc[0:24,:];  bfold = b1@T1 + b2@Wc[24:,:] + bc ----
__global__ void fold_misc_kernel(const float* __restrict__ Wc, const float* __restrict__ T1,
                                 const float* __restrict__ b1, const float* __restrict__ b2,
                                 const float* __restrict__ bc,
                                 float* __restrict__ Wbig, float* __restrict__ bfold)
{
  int tid = threadIdx.x;
  for (int i = tid; i < 24 * CH; i += 256) Wbig[i] = Wc[i];
  if (tid < CH) {
    float v = bc[tid];
    for (int k = 0; k < M2; ++k) v += b2[k] * Wc[(24 + k) * CH + tid];
    for (int i = 0; i < M1; ++i) v += b1[i] * T1[i * CH + tid];
    bfold[tid] = v;
  }
}

// ---------------- embed GEMM (64-row, single-buffer) for tiny frag matrix ----
#define EK 64
__global__ __launch_bounds__(256) void gemm_n32(
    const float* __restrict__ A, int M, int K,
    const float* __restrict__ W, const float* __restrict__ bias,
    float* __restrict__ C)
{
  __shared__ float As[64][65];
  __shared__ float Ws[EK][32];
  int tid = threadIdx.x;
  int row0 = blockIdx.x * 64;
  int tx = tid & 7, ty = tid >> 3;
  float c0[4] = {}, c1[4] = {};
  for (int k0 = 0; k0 < K; k0 += EK) {
    #pragma unroll
    for (int p = 0; p < 4; ++p) {
      int q = tid + p * 256;
      int r = q >> 4, c4 = (q & 15) * 4;
      int gr = row0 + r, gk = k0 + c4;
      float4 v = make_float4(0.f, 0.f, 0.f, 0.f);
      if (gr < M) {
        if (gk + 3 < K) v = *(const float4*)&A[(long long)gr * K + gk];
        else {
          float t[4] = {0.f, 0.f, 0.f, 0.f};
          for (int i = 0; i < 4; ++i) if (gk + i < K) t[i] = A[(long long)gr * K + gk + i];
          v = make_float4(t[0], t[1], t[2], t[3]);
        }
      }
      As[r][c4 + 0] = v.x; As[r][c4 + 1] = v.y; As[r][c4 + 2] = v.z; As[r][c4 + 3] = v.w;
    }
    #pragma unroll
    for (int p = 0; p < 2; ++p) {
      int q = tid + p * 256;
      int r = q >> 3, c4 = (q & 7) * 4;
      int gk = k0 + r;
      float4 v = make_float4(0.f, 0.f, 0.f, 0.f);
      if (gk < K) v = *(const float4*)&W[(long long)gk * 32 + c4];
      *(float4*)&Ws[r][c4] = v;
    }
    __syncthreads();
    #pragma unroll
    for (int kk = 0; kk < EK; ++kk) {
      float4 b = *(const float4*)&Ws[kk][tx * 4];
      float a0 = As[ty * 2][kk], a1 = As[ty * 2 + 1][kk];
      c0[0] += a0 * b.x; c0[1] += a0 * b.y; c0[2] += a0 * b.z; c0[3] += a0 * b.w;
      c1[0] += a1 * b.x; c1[1] += a1 * b.y; c1[2] += a1 * b.z; c1[3] += a1 * b.w;
    }
    __syncthreads();
  }
  float4 bb = *(const float4*)&bias[tx * 4];
  int gr0 = row0 + ty * 2;
  if (gr0 < M) {
    float4 v = make_float4(c0[0] + bb.x, c0[1] + bb.y, c0[2] + bb.z, c0[3] + bb.w);
    *(float4*)&C[(long long)gr0 * 32 + tx * 4] = v;
  }
  if (gr0 + 1 < M) {
    float4 v = make_float4(c1[0] + bb.x, c1[1] + bb.y, c1[2] + bb.z, c1[3] + bb.w);
    *(float4*)&C[(long long)(gr0 + 1) * 32 + tx * 4] = v;
  }
}

// ---- node-embed v3: thread-per-2-rows, K-quarter, W in LDS (broadcast), no K-loop barriers ----
// part[q][r][c] = A[r, k0:k0+kn] @ W[k0:k0+kn, :]
__global__ __launch_bounds__(256) void embed_part(
    const float* __restrict__ A, int M,
    const float* __restrict__ W,
    float* __restrict__ part)
{
  __shared__ float Wl[QK][32];   // 42KB
  int q = blockIdx.y;
  int k0 = q * QK;
  int kn = (q == 3) ? (NF - 3 * QK) : QK;   // 320 or 328
  int tid = threadIdx.x;
  // cooperative one-time W-chunk load (float4; base offset 16B-aligned)
  {
    const float4* src = (const float4*)(W + (long long)k0 * 32);
    float4* dst = (float4*)&Wl[0][0];
    int nf4 = kn * 8;
    for (int i = tid; i < nf4; i += 256) dst[i] = src[i];
  }
  __syncthreads();

  int r0 = blockIdx.x * 512 + tid;
  int r1 = r0 + 256;
  bool v0 = r0 < M, v1 = r1 < M;
  const float* a0p = A + (long long)(v0 ? r0 : 0) * NF + k0;
  const float* a1p = A + (long long)(v1 ? r1 : 0) * NF + k0;
  float4 acc0[8], acc1[8];
  #pragma unroll
  for (int c = 0; c < 8; ++c) {
    acc0[c] = make_float4(0.f, 0.f, 0.f, 0.f);
    acc1[c] = make_float4(0.f, 0.f, 0.f, 0.f);
  }
  int nf4 = kn >> 2;   // 82 or 80
  for (int f4 = 0; f4 < nf4; ++f4) {
    float4 a0 = *(const float4*)(a0p + f4 * 4);
    float4 a1 = *(const float4*)(a1p + f4 * 4);
    #pragma unroll
    for (int j = 0; j < 4; ++j) {
      float aj0 = (&a0.x)[j];
      float aj1 = (&a1.x)[j];
      const float4* wr = (const float4*)&Wl[f4 * 4 + j][0];
      #pragma unroll
      for (int c = 0; c < 8; ++c) {
        float4 w = wr[c];
        acc0[c].x += aj0 * w.x; acc0[c].y += aj0 * w.y;
        acc0[c].z += aj0 * w.z; acc0[c].w += aj0 * w.w;
        acc1[c].x += aj1 * w.x; acc1[c].y += aj1 * w.y;
        acc1[c].z += aj1 * w.z; acc1[c].w += aj1 * w.w;
      }
    }
  }
  float* p = part + (long long)q * M * 32;
  if (v0) {
    float4* o = (float4*)(p + (long long)r0 * 32);
    #pragma unroll
    for (int c = 0; c < 8; ++c) o[c] = acc0[c];
  }
  if (v1) {
    float4* o = (float4*)(p + (long long)r1 * 32);
    #pragma unroll
    for (int c = 0; c < 8; ++c) o[c] = acc1[c];
  }
}

// ---- reduce 4 partials + bias -> x0 ----
__global__ __launch_bounds__(256) void embed_reduce(
    const float* __restrict__ part, const float* __restrict__ bias,
    float* __restrict__ C, int M)
{
  long long i = (long long)blockIdx.x * 256 + threadIdx.x;  // float4 index
  long long tot = (long long)M * 8;
  if (i >= tot) return;
  long long stride = tot;
  const float4* p = (const float4*)part;
  float4 v = p[i];
  float4 v1 = p[i + stride];
  float4 v2 = p[i + 2 * stride];
  float4 v3 = p[i + 3 * stride];
  float4 bb = ((const float4*)bias)[i & 7];
  float4 o;
  o.x = ((v.x + v1.x) + v2.x) + v3.x + bb.x;
  o.y = ((v.y + v1.y) + v2.y) + v3.y + bb.y;
  o.z = ((v.z + v1.z) + v2.z) + v3.z + bb.z;
  o.w = ((v.w + v1.w) + v2.w) + v3.w + bb.w;
  ((float4*)C)[i] = o;
}

// ---------------- CSR build ----------------
__global__ void zero_deg_kernel(int* __restrict__ degp, long long n)
{
  long long i = (long long)blockIdx.x * 256 + threadIdx.x;
  if (i < n) degp[i] = 0;
}
__global__ void rank_kernel(const int* __restrict__ ei, int E,
                            int* __restrict__ degp, int* __restrict__ rank)
{
  int e = blockIdx.x * 256 + threadIdx.x;
  if (e < E) rank[e] = atomicAdd(&degp[(long long)ei[E + e] * DPAD], 1);
}
__global__ void partial_kernel(const int* __restrict__ degp, int N, int* __restrict__ partial)
{
  __shared__ int sd[256];
  int i = blockIdx.x * 256 + threadIdx.x;
  sd[threadIdx.x] = (i < N) ? degp[(long long)i * DPAD] : 0;
  __syncthreads();
  for (int off = 128; off > 0; off >>= 1) {
    if (threadIdx.x < off) sd[threadIdx.x] += sd[threadIdx.x + off];
    __syncthreads();
  }
  if (threadIdx.x == 0) partial[blockIdx.x] = sd[0];
}
__global__ void scanp_kernel(int* __restrict__ partial, int NB)
{
  __shared__ int sd[512];
  int t = threadIdx.x;
  int v = (t < NB) ? partial[t] : 0;
  sd[t] = v;
  __syncthreads();
  for (int off = 1; off < 512; off <<= 1) {
    int u = (t >= off) ? sd[t - off] : 0;
    __syncthreads();
    sd[t] += u;
    __syncthreads();
  }
  if (t < NB) partial[t] = sd[t] - v;   // exclusive
}
__global__ void scan_final_kernel(const int* __restrict__ degp, int N,
                                  const int* __restrict__ partial,
                                  int* __restrict__ rowptr)
{
  __shared__ int sd[256];
  int i = blockIdx.x * 256 + threadIdx.x;
  int t = threadIdx.x;
  int v = (i < N) ? degp[(long long)i * DPAD] : 0;
  sd[t] = v;
  __syncthreads();
  for (int off = 1; off < 256; off <<= 1) {
    int u = (t >= off) ? sd[t - off] : 0;
    __syncthreads();
    sd[t] += u;
    __syncthreads();
  }
  if (i < N) {
    int excl = partial[blockIdx.x] + sd[t] - v;
    rowptr[i] = excl;
    if (i == N - 1) rowptr[N] = excl + v;
  }
}
__global__ void scatter_plain_kernel(const int* __restrict__ ei, int E,
                                     const int* __restrict__ rowptr,
                                     const int* __restrict__ rank,
                                     int* __restrict__ csr)
{
  int e = blockIdx.x * 256 + threadIdx.x;
  if (e >= E) return;
  int dn = ei[E + e];
  csr[rowptr[dn] + rank[e]] = ei[e];
}

// ---- fused projection + dst-logit: h = x@W (fp16, 64B/node); d = h·adst ----
template<int H, int C>
__global__ __launch_bounds__(256) void proj_sd_kernel(
    const float* __restrict__ x, const float* __restrict__ W,
    const float* __restrict__ adst,
    unsigned* __restrict__ hp, float* __restrict__ dv, int N)
{
  __shared__ float Ws[CH][CH];
  __shared__ float al[CH];
  int tid = threadIdx.x;
  for (int i = tid; i < CH * CH; i += 256) Ws[i >> 5][i & 31] = W[i];
  if (tid < CH) al[tid] = adst[tid];
  __syncthreads();
  int n = blockIdx.x * 256 + tid;
  if (n >= N) return;
  float xr[CH];
  #pragma unroll
  for (int j = 0; j < CH / 4; ++j) {
    float4 v = *(const float4*)&x[(long long)n * CH + j * 4];
    xr[j * 4] = v.x; xr[j * 4 + 1] = v.y; xr[j * 4 + 2] = v.z; xr[j * 4 + 3] = v.w;
  }
  float hr[CH] = {};
  #pragma unroll
  for (int c = 0; c < CH; ++c) {
    float xc = xr[c];
    #pragma unroll
    for (int j4 = 0; j4 < CH / 4; ++j4) {
      float4 w = *(const float4*)&Ws[c][j4 * 4];
      hr[j4 * 4] += xc * w.x; hr[j4 * 4 + 1] += xc * w.y;
      hr[j4 * 4 + 2] += xc * w.z; hr[j4 * 4 + 3] += xc * w.w;
    }
  }
  // pack 32 fp16 = 64B
  unsigned pk[16];
  #pragma unroll
  for (int j = 0; j < 16; ++j)
    pk[j] = (unsigned)f2h(hr[2 * j]) | ((unsigned)f2h(hr[2 * j + 1]) << 16);
  uint4* hq = (uint4*)&hp[(long long)n * 16];
  #pragma unroll
  for (int j = 0; j < 4; ++j)
    hq[j] = make_uint4(pk[4 * j], pk[4 * j + 1], pk[4 * j + 2], pk[4 * j + 3]);
  #pragma unroll
  for (int hh = 0; hh < H; ++hh) {
    float dd = 0.f;
    #pragma unroll
    for (int c = 0; c < C; ++c) dd += hr[hh * C + c] * al[hh * C + c];
    dv[(long long)n * H + hh] = dd;
  }
}

// ---------------- GAT gather (r11 config): 16 lanes/edge, 4 slots, 4x unroll ----
template<int H, int C>
__global__ __launch_bounds__(256) void gat_gather_kernel(
    const int* __restrict__ rowptr, const int* __restrict__ csr,
    const unsigned* __restrict__ hp, const float* __restrict__ asrc,
    const float* __restrict__ dv, const float* __restrict__ bias,
    float* __restrict__ xout, int N, int do_elu)
{
  int wid = threadIdx.x >> 6;
  int lane = threadIdx.x & 63;
  int n = blockIdx.x * 4 + wid;
  if (n >= N) return;
  int cpair = lane & 15;
  int slot = lane >> 4;
  int ch = cpair * 2;
  int hh = (C == HID1) ? (cpair >> 1) : 0;
  float a0 = asrc[ch], a1 = asrc[ch + 1];
  float dn = dv[(long long)n * H + hh];

  auto sred = [&](float p) {
    p += __shfl_xor(p, 1, 64);
    if (C == CH) {
      p += __shfl_xor(p, 2, 64);
      p += __shfl_xor(p, 4, 64);
      p += __shfl_xor(p, 8, 64);
    }
    return p;
  };

  float acc0 = 0.f, acc1 = 0.f, z = 0.f;
  {
    unsigned u = hp[(long long)n * 16 + cpair];
    float h0 = h2f((unsigned short)(u & 0xffff));
    float h1 = h2f((unsigned short)(u >> 16));
    float s = sred(h0 * a0 + h1 * a1);
    if (slot == 0) {
      float lg = s + dn;
      lg = lg > 0.f ? lg : 0.2f * lg;
      float w = expf(lg);
      z = w; acc0 = w * h0; acc1 = w * h1;
    }
  }
  int start = rowptr[n], end = rowptr[n + 1];
  for (int base = start; base < end; base += 64) {
    int m = end - base; if (m > 64) m = 64;
    int idx = (base + lane < end) ? csr[base + lane] : 0;
    int k = slot;
    for (; k + 12 < m; k += 16) {
      int si0 = __shfl(idx, k, 64);
      int si1 = __shfl(idx, k + 4, 64);
      int si2 = __shfl(idx, k + 8, 64);
      int si3 = __shfl(idx, k + 12, 64);
      unsigned u0 = hp[(long long)si0 * 16 + cpair];
      unsigned u1 = hp[(long long)si1 * 16 + cpair];
      unsigned u2 = hp[(long long)si2 * 16 + cpair];
      unsigned u3 = hp[(long long)si3 * 16 + cpair];
      float h00 = h2f((unsigned short)(u0 & 0xffff)), h01 = h2f((unsigned short)(u0 >> 16));
      float h10 = h2f((unsigned short)(u1 & 0xffff)), h11 = h2f((unsigned short)(u1 >> 16));
      float h20 = h2f((unsigned short)(u2 & 0xffff)), h21 = h2f((unsigned short)(u2 >> 16));
      float h30 = h2f((unsigned short)(u3 & 0xffff)), h31 = h2f((unsigned short)(u3 >> 16));
      float s0 = sred(h00 * a0 + h01 * a1);
      float s1 = sred(h10 * a0 + h11 * a1);
      float s2 = sred(h20 * a0 + h21 * a1);
      float s3 = sred(h30 * a0 + h31 * a1);
      float lg0 = s0 + dn; lg0 = lg0 > 0.f ? lg0 : 0.2f * lg0;
      float lg1 = s1 + dn; lg1 = lg1 > 0.f ? lg1 : 0.2f * lg1;
      float lg2 = s2 + dn; lg2 = lg2 > 0.f ? lg2 : 0.2f * lg2;
      float lg3 = s3 + dn; lg3 = lg3 > 0.f ? lg3 : 0.2f * lg3;
      float w0 = expf(lg0), w1 = expf(lg1), w2 = expf(lg2), w3 = expf(lg3);
      z += (w0 + w1) + (w2 + w3);
      acc0 += w0 * h00 + w1 * h10 + w2 * h20 + w3 * h30;
      acc1 += w0 * h01 + w1 * h11 + w2 * h21 + w3 * h31;
    }
    for (; k < m; k += 4) {
      int si0 = __shfl(idx, k, 64);
      unsigned u0 = hp[(long long)si0 * 16 + cpair];
      float h00 = h2f((unsigned short)(u0 & 0xffff)), h01 = h2f((unsigned short)(u0 >> 16));
      float s0 = sred(h00 * a0 + h01 * a1);
      float lg0 = s0 + dn; lg0 = lg0 > 0.f ? lg0 : 0.2f * lg0;
      float w0 = expf(lg0);
      z += w0;
      acc0 += w0 * h00;
      acc1 += w0 * h01;
    }
  }
  acc0 += __shfl_xor(acc0, 16, 64); acc0 += __shfl_xor(acc0, 32, 64);
  acc1 += __shfl_xor(acc1, 16, 64); acc1 += __shfl_xor(acc1, 32, 64);
  z    += __shfl_xor(z, 16, 64);    z    += __shfl_xor(z, 32, 64);
  if (slot == 0) {
    float v0 = acc0 / z + bias[ch];
    float v1 = acc1 / z + bias[ch + 1];
    if (do_elu) {
      v0 = v0 > 0.f ? v0 : (expf(v0) - 1.f);
      v1 = v1 > 0.f ? v1 : (expf(v1) - 1.f);
    }
    *(float2*)&xout[(long long)n * 32 + ch] = make_float2(v0, v1);
  }
}

// ---------------- final fragment-attention pooling ----------------
__global__ __launch_bounds__(256) void pool_kernel(
    const float* __restrict__ x, const float* __restrict__ ys,
    const float* __restrict__ Wfin, const float* __restrict__ bfin,
    float* __restrict__ out, int NB)
{
  __shared__ float ysl[FRAG][CH];
  __shared__ float tl[FRAG];
  int b = blockIdx.y;
  int tid = threadIdx.x;
  for (int idx = tid; idx < FRAG * CH; idx += 256)
    ysl[idx >> 5][idx & 31] = ys[(long long)b * FRAG * CH + idx];
  __syncthreads();
  if (tid < FRAG) {
    float t = 0.f;
    #pragma unroll
    for (int dd = 0; dd < CH; ++dd) t += ysl[tid][dd] * Wfin[dd];
    tl[tid] = t;
  }
  __syncthreads();
  int n = blockIdx.x * 256 + tid;
  if (n >= NB) return;
  const float* xr = x + ((long long)b * NB + n) * CH;
  float xreg[CH];
  #pragma unroll
  for (int dd = 0; dd < CH; ++dd) xreg[dd] = xr[dd];
  float mx = -1e30f;
  for (int f = 0; f < FRAG; ++f) {
    float l = 0.f;
    #pragma unroll
    for (int dd = 0; dd < CH; ++dd) l += xreg[dd] * ysl[f][dd];
    mx = fmaxf(mx, l);
  }
  float se = 0.f, sw = 0.f;
  for (int f = 0; f < FRAG; ++f) {
    float l = 0.f;
    #pragma unroll
    for (int dd = 0; dd < CH; ++dd) l += xreg[dd] * ysl[f][dd];
    float e = expf(l - mx);
    se += e; sw += e * tl[f];
  }
  float logit = sw / se + bfin[0];
  out[(long long)b * NB + n] = 1.f / (1.f + expf(-logit));
}

// ---------------- host orchestration ----------------
extern "C" void kernel_launch(void* const* d_in, const int* in_sizes, int n_in,
                              void* d_out, int out_size, void* d_ws, size_t ws_size,
                              hipStream_t stream)
{
  const float* feats = (const float*)d_in[0];
  const int*   ei    = (const int*)d_in[1];
  const float* frag  = (const float*)d_in[3];
  const float* W1    = (const float*)d_in[4];
  const float* b1    = (const float*)d_in[5];
  const float* W2    = (const float*)d_in[6];
  const float* b2    = (const float*)d_in[7];
  const float* Wc    = (const float*)d_in[8];
  const float* bc    = (const float*)d_in[9];
  const float* g1W   = (const float*)d_in[10];
  const float* g1as  = (const float*)d_in[11];
  const float* g1ad  = (const float*)d_in[12];
  const float* g1b   = (const float*)d_in[13];
  const float* g2W   = (const float*)d_in[14];
  const float* g2as  = (const float*)d_in[15];
  const float* g2ad  = (const float*)d_in[16];
  const float* g2b   = (const float*)d_in[17];
  const float* Wfin  = (const float*)d_in[18];
  const float* bfin  = (const float*)d_in[19];

  const int N  = in_sizes[0] / NF;     // 100000
  const int E  = in_sizes[1] / 2;      // 3200000
  const int BF = in_sizes[3] / NF;     // 400
  const int NB = N / NBATCH;           // 12500

  char* ws = (char*)d_ws;
  size_t off = 0;
  auto walloc = [&](size_t bytes) -> void* {
    void* p = ws + off;
    off += (bytes + 255) & ~(size_t)255;
    return p;
  };
  float*    T1     = (float*)walloc((size_t)M1 * CH * 4);
  float*    Wbig   = (float*)walloc((size_t)NF * CH * 4);
  float*    bfold  = (float*)walloc((size_t)CH * 4);
  float*    x0     = (float*)walloc((size_t)N * CH * 4);
  float*    x1     = (float*)walloc((size_t)N * CH * 4);
  unsigned* hbuf   = (unsigned*)walloc((size_t)N * 16 * 4);    // 64B/node fp16 h
  float*    dbuf   = (float*)walloc((size_t)N * NHEAD1 * 4);
  float*    ysb    = (float*)walloc((size_t)BF * CH * 4);
  int*      degp   = (int*)walloc((size_t)N * DPAD * 4);
  int*      rowptr = (int*)walloc((size_t)(N + 1) * 4);
  int*      rank   = (int*)walloc((size_t)E * 4);
  int*      part   = (int*)walloc((size_t)512 * 4);
  int*      csr    = (int*)walloc((size_t)E * 4);
  float*    pembed = (float*)walloc((size_t)4 * N * CH * 4);   // 4 partial bufs
  (void)ws_size; (void)n_in; (void)out_size;

  // ---- weight folding (tiny): T1 = W2 @ Wc[24:,:]; Wbig[24:,:] = W1 @ T1 ----
  {
    dim3 g1(1, ceil_div(M1, TM));
    gemm_bias<<<g1, 256, 0, stream>>>(W2, M2, Wc + 24 * CH, CH, nullptr, T1, CH,
                                      M1, CH, M2, 0);
    dim3 g2(1, ceil_div(NF - 24, TM));
    gemm_bias<<<g2, 256, 0, stream>>>(W1, M1, T1, CH, nullptr, Wbig + 24 * CH, CH,
                                      NF - 24, CH, M1, 0);
    fold_misc_kernel<<<1, 256, 0, stream>>>(Wc, T1, b1, b2, bc, Wbig, bfold);
  }

  // ---- node embed v3: barrier-free partial GEMM + reduce ----
  {
    dim3 g(ceil_div(N, 512), 4);
    embed_part<<<g, 256, 0, stream>>>(feats, N, Wbig, pembed);
    long long tot = (long long)N * 8;
    embed_reduce<<<(int)((tot + 255) / 256), 256, 0, stream>>>(pembed, bfold, x0, N);
  }

  // ---- CSR build: zero + standalone rank + scan + scatter ----
  {
    long long npad = (long long)N * DPAD;
    int nb = ceil_div(N, 256);
    zero_deg_kernel<<<(int)((npad + 255) / 256), 256, 0, stream>>>(degp, npad);
    rank_kernel<<<ceil_div(E, 256), 256, 0, stream>>>(ei, E, degp, rank);
    partial_kernel<<<nb, 256, 0, stream>>>(degp, N, part);
    scanp_kernel<<<1, 512, 0, stream>>>(part, nb);
    scan_final_kernel<<<nb, 256, 0, stream>>>(degp, N, part, rowptr);
    scatter_plain_kernel<<<ceil_div(E, 256), 256, 0, stream>>>(ei, E, rowptr, rank, csr);
  }

  // ---- fragment embed ----
  gemm_n32<<<ceil_div(BF, 64), 256, 0, stream>>>(frag, BF, NF, Wbig, bfold, ysb);

  // ---- GAT conv helper ----
  auto conv = [&](const float* xin, float* xout, const float* W, const float* as_,
                  const float* ad_, const float* bias, int H, int do_elu) {
    if (H == NHEAD1) {
      proj_sd_kernel<NHEAD1, HID1><<<ceil_div(N, 256), 256, 0, stream>>>(
          xin, W, ad_, hbuf, dbuf, N);
      gat_gather_kernel<NHEAD1, HID1><<<ceil_div(N, 4), 256, 0, stream>>>(
          rowptr, csr, hbuf, as_, dbuf, bias, xout, N, do_elu);
    } else {
      proj_sd_kernel<1, CH><<<ceil_div(N, 256), 256, 0, stream>>>(
          xin, W, ad_, hbuf, dbuf, N);
      gat_gather_kernel<1, CH><<<ceil_div(N, 4), 256, 0, stream>>>(
          rowptr, csr, hbuf, as_, dbuf, bias, xout, N, do_elu);
    }
  };

  for (int l = 0; l < NLAYER; ++l) {
    conv(x0, x1, g1W + l * CH * CH, g1as + l * NHEAD1 * HID1, g1ad + l * NHEAD1 * HID1,
         g1b + l * CH, NHEAD1, 1);
    conv(x1, x0, g2W + l * CH * CH, g2as + l * CH, g2ad + l * CH,
         g2b + l * CH, 1, 0);
  }

  // ---- final pooling ----
  pool_kernel<<<dim3(ceil_div(NB, 256), NBATCH), 256, 0, stream>>>(
      x0, ysb, Wfin, bfin, (float*)d_out, NB);
}

// Round 18
// 1277.612 us; speedup vs baseline: 1.1977x; 1.1977x over previous
//
#include <hip/hip_runtime.h>
#include <hip/hip_bf16.h>

#define NF 1304
#define M1 652
#define M2 326
#define CH 32
#define NHEAD1 8
#define HID1 4
#define NLAYER 3
#define FRAG 50
#define NBATCH 8
#define DPAD 32   // degree counter padding (128B line per node)

static inline int ceil_div(int a, int b){ return (a + b - 1)/b; }

__device__ __forceinline__ unsigned short f2h(float f){
  _Float16 h = (_Float16)f;
  unsigned short u;
  __builtin_memcpy(&u, &h, 2);
  return u;
}
__device__ __forceinline__ float h2f(unsigned short u){
  _Float16 h;
  __builtin_memcpy(&h, &u, 2);
  return (float)h;
}

// ---------------- generic fp32 tiled GEMM (used only for tiny weight folds) ----
#define TM 64
#define TN 64
#define TKK 16
__global__ __launch_bounds__(256) void gemm_bias(
    const float* __restrict__ A, int lda,
    const float* __restrict__ B, int ldb,
    const float* __restrict__ bias,
    float* __restrict__ C, int ldc,
    int M, int N, int K, int acc)
{
  __shared__ float As[TKK][TM + 1];
  __shared__ float Bs[TKK][TN];
  int tid = threadIdx.x;
  int tx = tid & 15, ty = tid >> 4;
  int row0 = blockIdx.y * TM, col0 = blockIdx.x * TN;
  float c[4][4] = {};
  for (int k0 = 0; k0 < K; k0 += TKK) {
    #pragma unroll
    for (int p = 0; p < 4; ++p) {
      int r = (tid >> 4) + p * 16;
      int kk = tid & 15;
      int gr = row0 + r, gk = k0 + kk;
      float v = 0.f;
      if (gr < M && gk < K) v = A[(long long)gr * lda + gk];
      As[kk][r] = v;
    }
    #pragma unroll
    for (int p = 0; p < 4; ++p) {
      int kk = (tid >> 6) + p * 4;
      int cc = tid & 63;
      int gk = k0 + kk, gc = col0 + cc;
      float v = 0.f;
      if (gk < K && gc < N) v = B[(long long)gk * ldb + gc];
      Bs[kk][cc] = v;
    }
    __syncthreads();
    #pragma unroll
    for (int kk = 0; kk < TKK; ++kk) {
      float a[4], b[4];
      #pragma unroll
      for (int i = 0; i < 4; ++i) a[i] = As[kk][ty + 16 * i];
      #pragma unroll
      for (int j = 0; j < 4; ++j) b[j] = Bs[kk][tx + 16 * j];
      #pragma unroll
      for (int i = 0; i < 4; ++i)
        #pragma unroll
        for (int j = 0; j < 4; ++j)
          c[i][j] += a[i] * b[j];
    }
    __syncthreads();
  }
  #pragma unroll
  for (int i = 0; i < 4; ++i) {
    int gr = row0 + ty + 16 * i;
    if (gr >= M) continue;
    #pragma unroll
    for (int j = 0; j < 4; ++j) {
      int gc = col0 + tx + 16 * j;
      if (gc >= N) continue;
      float v = c[i][j];
      if (bias) v += bias[gc];
      if (acc) v += C[(long long)gr * ldc + gc];
      C[(long long)gr * ldc + gc] = v;
    }
  }
}

// ---- fold misc: Wbig[0:24,:] = Wc[0:24,:];  bfold = b1@T1 + b2@Wc[24:,:] + bc ----
__global__ void fold_misc_kernel(const float* __restrict__ Wc, const float* __restrict__ T1,
                                 const float* __restrict__ b1, const float* __restrict__ b2,
                                 const float* __restrict__ bc,
                                 float* __restrict__ Wbig, float* __restrict__ bfold)
{
  int tid = threadIdx.x;
  for (int i = tid; i < 24 * CH; i += 256) Wbig[i] = Wc[i];
  if (tid < CH) {
    float v = bc[tid];
    for (int k = 0; k < M2; ++k) v += b2[k] * Wc[(24 + k) * CH + tid];
    for (int i = 0; i < M1; ++i) v += b1[i] * T1[i * CH + tid];
    bfold[tid] = v;
  }
}

// ---------------- embed GEMM (64-row, single-buffer) for tiny frag matrix ----
#define EK 64
__global__ __launch_bounds__(256) void gemm_n32(
    const float* __restrict__ A, int M, int K,
    const float* __restrict__ W, const float* __restrict__ bias,
    float* __restrict__ C)
{
  __shared__ float As[64][65];
  __shared__ float Ws[EK][32];
  int tid = threadIdx.x;
  int row0 = blockIdx.x * 64;
  int tx = tid & 7, ty = tid >> 3;
  float c0[4] = {}, c1[4] = {};
  for (int k0 = 0; k0 < K; k0 += EK) {
    #pragma unroll
    for (int p = 0; p < 4; ++p) {
      int q = tid + p * 256;
      int r = q >> 4, c4 = (q & 15) * 4;
      int gr = row0 + r, gk = k0 + c4;
      float4 v = make_float4(0.f, 0.f, 0.f, 0.f);
      if (gr < M) {
        if (gk + 3 < K) v = *(const float4*)&A[(long long)gr * K + gk];
        else {
          float t[4] = {0.f, 0.f, 0.f, 0.f};
          for (int i = 0; i < 4; ++i) if (gk + i < K) t[i] = A[(long long)gr * K + gk + i];
          v = make_float4(t[0], t[1], t[2], t[3]);
        }
      }
      As[r][c4 + 0] = v.x; As[r][c4 + 1] = v.y; As[r][c4 + 2] = v.z; As[r][c4 + 3] = v.w;
    }
    #pragma unroll
    for (int p = 0; p < 2; ++p) {
      int q = tid + p * 256;
      int r = q >> 3, c4 = (q & 7) * 4;
      int gk = k0 + r;
      float4 v = make_float4(0.f, 0.f, 0.f, 0.f);
      if (gk < K) v = *(const float4*)&W[(long long)gk * 32 + c4];
      *(float4*)&Ws[r][c4] = v;
    }
    __syncthreads();
    #pragma unroll
    for (int kk = 0; kk < EK; ++kk) {
      float4 b = *(const float4*)&Ws[kk][tx * 4];
      float a0 = As[ty * 2][kk], a1 = As[ty * 2 + 1][kk];
      c0[0] += a0 * b.x; c0[1] += a0 * b.y; c0[2] += a0 * b.z; c0[3] += a0 * b.w;
      c1[0] += a1 * b.x; c1[1] += a1 * b.y; c1[2] += a1 * b.z; c1[3] += a1 * b.w;
    }
    __syncthreads();
  }
  float4 bb = *(const float4*)&bias[tx * 4];
  int gr0 = row0 + ty * 2;
  if (gr0 < M) {
    float4 v = make_float4(c0[0] + bb.x, c0[1] + bb.y, c0[2] + bb.z, c0[3] + bb.w);
    *(float4*)&C[(long long)gr0 * 32 + tx * 4] = v;
  }
  if (gr0 + 1 < M) {
    float4 v = make_float4(c1[0] + bb.x, c1[1] + bb.y, c1[2] + bb.z, c1[3] + bb.w);
    *(float4*)&C[(long long)(gr0 + 1) * 32 + tx * 4] = v;
  }
}

// ---- node-embed GEMM v2: 32-row tile, register-prefetch double-buffer, rank tail ----
__global__ __launch_bounds__(256) void gemm_n32_rank(
    const float* __restrict__ A, int M, int K,
    const float* __restrict__ W, const float* __restrict__ bias,
    float* __restrict__ C,
    const int* __restrict__ ei, int E, int chunk,
    int* __restrict__ degp, int* __restrict__ rank)
{
  __shared__ float As[32][65];     // 8320 B
  __shared__ float Ws[EK][32];     // 8192 B
  int tid = threadIdx.x;
  int row0 = blockIdx.x * 32;
  int tx = tid & 7, ty = tid >> 3;   // ty = row (0..31), tx = col quad
  float4 pa[2], pw[2];
  auto loadA = [&](int k0, float4* dst) {
    #pragma unroll
    for (int p = 0; p < 2; ++p) {
      int q = tid + p * 256;
      int r = q >> 4, c4 = (q & 15) * 4;
      int gr = row0 + r, gk = k0 + c4;
      float4 v = make_float4(0.f, 0.f, 0.f, 0.f);
      if (gr < M) {
        if (gk + 3 < K) v = *(const float4*)&A[(long long)gr * K + gk];
        else {
          float t[4] = {0.f, 0.f, 0.f, 0.f};
          for (int i = 0; i < 4; ++i) if (gk + i < K) t[i] = A[(long long)gr * K + gk + i];
          v = make_float4(t[0], t[1], t[2], t[3]);
        }
      }
      dst[p] = v;
    }
  };
  auto loadW = [&](int k0, float4* dst) {
    #pragma unroll
    for (int p = 0; p < 2; ++p) {
      int q = tid + p * 256;
      int r = q >> 3, c4 = (q & 7) * 4;
      int gk = k0 + r;
      float4 v = make_float4(0.f, 0.f, 0.f, 0.f);
      if (gk < K) v = *(const float4*)&W[(long long)gk * 32 + c4];
      dst[p] = v;
    }
  };
  auto store = [&](const float4* sa, const float4* sw) {
    #pragma unroll
    for (int p = 0; p < 2; ++p) {
      int q = tid + p * 256;
      int r = q >> 4, c4 = (q & 15) * 4;
      As[r][c4 + 0] = sa[p].x; As[r][c4 + 1] = sa[p].y;
      As[r][c4 + 2] = sa[p].z; As[r][c4 + 3] = sa[p].w;
      int rw = q >> 3, cw = (q & 7) * 4;
      *(float4*)&Ws[rw][cw] = sw[p];
    }
  };

  float c0[4] = {};
  loadA(0, pa); loadW(0, pw);
  store(pa, pw);
  __syncthreads();
  for (int k0 = 0; k0 < K; k0 += EK) {
    bool more = (k0 + EK < K);
    if (more) { loadA(k0 + EK, pa); loadW(k0 + EK, pw); }  // in flight during compute
    #pragma unroll
    for (int kk = 0; kk < EK; ++kk) {
      float4 b = *(const float4*)&Ws[kk][tx * 4];
      float a = As[ty][kk];
      c0[0] += a * b.x; c0[1] += a * b.y; c0[2] += a * b.z; c0[3] += a * b.w;
    }
    __syncthreads();
    if (more) {
      store(pa, pw);
      __syncthreads();
    }
  }
  int gr = row0 + ty;
  if (gr < M) {
    float4 bb = *(const float4*)&bias[tx * 4];
    float4 v = make_float4(c0[0] + bb.x, c0[1] + bb.y, c0[2] + bb.z, c0[3] + bb.w);
    *(float4*)&C[(long long)gr * 32 + tx * 4] = v;
  }
  // rank tail: this block's edge chunk (latency-bound; overlaps other blocks' GEMM)
  int e0 = blockIdx.x * chunk;
  int e1 = e0 + chunk; if (e1 > E) e1 = E;
  for (int e = e0 + threadIdx.x; e < e1; e += 256)
    rank[e] = atomicAdd(&degp[(long long)ei[E + e] * DPAD], 1);
}

// ---------------- CSR build helpers ----------------
__global__ void zero_deg_kernel(int* __restrict__ degp, long long n)
{
  long long i = (long long)blockIdx.x * 256 + threadIdx.x;
  if (i < n) degp[i] = 0;
}
__global__ void partial_kernel(const int* __restrict__ degp, int N, int* __restrict__ partial)
{
  __shared__ int sd[256];
  int i = blockIdx.x * 256 + threadIdx.x;
  sd[threadIdx.x] = (i < N) ? degp[(long long)i * DPAD] : 0;
  __syncthreads();
  for (int off = 128; off > 0; off >>= 1) {
    if (threadIdx.x < off) sd[threadIdx.x] += sd[threadIdx.x + off];
    __syncthreads();
  }
  if (threadIdx.x == 0) partial[blockIdx.x] = sd[0];
}
__global__ void scanp_kernel(int* __restrict__ partial, int NB)
{
  __shared__ int sd[512];
  int t = threadIdx.x;
  int v = (t < NB) ? partial[t] : 0;
  sd[t] = v;
  __syncthreads();
  for (int off = 1; off < 512; off <<= 1) {
    int u = (t >= off) ? sd[t - off] : 0;
    __syncthreads();
    sd[t] += u;
    __syncthreads();
  }
  if (t < NB) partial[t] = sd[t] - v;   // exclusive
}
__global__ void scan_final_kernel(const int* __restrict__ degp, int N,
                                  const int* __restrict__ partial,
                                  int* __restrict__ rowptr)
{
  __shared__ int sd[256];
  int i = blockIdx.x * 256 + threadIdx.x;
  int t = threadIdx.x;
  int v = (i < N) ? degp[(long long)i * DPAD] : 0;
  sd[t] = v;
  __syncthreads();
  for (int off = 1; off < 256; off <<= 1) {
    int u = (t >= off) ? sd[t - off] : 0;
    __syncthreads();
    sd[t] += u;
    __syncthreads();
  }
  if (i < N) {
    int excl = partial[blockIdx.x] + sd[t] - v;
    rowptr[i] = excl;
    if (i == N - 1) rowptr[N] = excl + v;
  }
}
__global__ void scatter_plain_kernel(const int* __restrict__ ei, int E,
                                     const int* __restrict__ rowptr,
                                     const int* __restrict__ rank,
                                     int* __restrict__ csr)
{
  int e = blockIdx.x * 256 + threadIdx.x;
  if (e >= E) return;
  int dn = ei[E + e];
  csr[rowptr[dn] + rank[e]] = ei[e];
}

// ---- fused projection + dst-logit: h = x@W (fp16, 64B/node); d = h·adst ----
template<int H, int C>
__global__ __launch_bounds__(256) void proj_sd_kernel(
    const float* __restrict__ x, const float* __restrict__ W,
    const float* __restrict__ adst,
    unsigned* __restrict__ hp, float* __restrict__ dv, int N)
{
  __shared__ float Ws[CH][CH];
  __shared__ float al[CH];
  int tid = threadIdx.x;
  for (int i = tid; i < CH * CH; i += 256) Ws[i >> 5][i & 31] = W[i];
  if (tid < CH) al[tid] = adst[tid];
  __syncthreads();
  int n = blockIdx.x * 256 + tid;
  if (n >= N) return;
  float xr[CH];
  #pragma unroll
  for (int j = 0; j < CH / 4; ++j) {
    float4 v = *(const float4*)&x[(long long)n * CH + j * 4];
    xr[j * 4] = v.x; xr[j * 4 + 1] = v.y; xr[j * 4 + 2] = v.z; xr[j * 4 + 3] = v.w;
  }
  float hr[CH] = {};
  #pragma unroll
  for (int c = 0; c < CH; ++c) {
    float xc = xr[c];
    #pragma unroll
    for (int j4 = 0; j4 < CH / 4; ++j4) {
      float4 w = *(const float4*)&Ws[c][j4 * 4];
      hr[j4 * 4] += xc * w.x; hr[j4 * 4 + 1] += xc * w.y;
      hr[j4 * 4 + 2] += xc * w.z; hr[j4 * 4 + 3] += xc * w.w;
    }
  }
  // pack 32 fp16 = 64B
  unsigned pk[16];
  #pragma unroll
  for (int j = 0; j < 16; ++j)
    pk[j] = (unsigned)f2h(hr[2 * j]) | ((unsigned)f2h(hr[2 * j + 1]) << 16);
  uint4* hq = (uint4*)&hp[(long long)n * 16];
  #pragma unroll
  for (int j = 0; j < 4; ++j)
    hq[j] = make_uint4(pk[4 * j], pk[4 * j + 1], pk[4 * j + 2], pk[4 * j + 3]);
  #pragma unroll
  for (int hh = 0; hh < H; ++hh) {
    float dd = 0.f;
    #pragma unroll
    for (int c = 0; c < C; ++c) dd += hr[hh * C + c] * al[hh * C + c];
    dv[(long long)n * H + hh] = dd;
  }
}

// ---------------- GAT gather (r11 config): 16 lanes/edge, 4 slots, 4x unroll ----
template<int H, int C>
__global__ __launch_bounds__(256) void gat_gather_kernel(
    const int* __restrict__ rowptr, const int* __restrict__ csr,
    const unsigned* __restrict__ hp, const float* __restrict__ asrc,
    const float* __restrict__ dv, const float* __restrict__ bias,
    float* __restrict__ xout, int N, int do_elu)
{
  int wid = threadIdx.x >> 6;
  int lane = threadIdx.x & 63;
  int n = blockIdx.x * 4 + wid;
  if (n >= N) return;
  int cpair = lane & 15;
  int slot = lane >> 4;
  int ch = cpair * 2;
  int hh = (C == HID1) ? (cpair >> 1) : 0;
  float a0 = asrc[ch], a1 = asrc[ch + 1];
  float dn = dv[(long long)n * H + hh];

  auto sred = [&](float p) {
    p += __shfl_xor(p, 1, 64);
    if (C == CH) {
      p += __shfl_xor(p, 2, 64);
      p += __shfl_xor(p, 4, 64);
      p += __shfl_xor(p, 8, 64);
    }
    return p;
  };

  float acc0 = 0.f, acc1 = 0.f, z = 0.f;
  {
    unsigned u = hp[(long long)n * 16 + cpair];
    float h0 = h2f((unsigned short)(u & 0xffff));
    float h1 = h2f((unsigned short)(u >> 16));
    float s = sred(h0 * a0 + h1 * a1);
    if (slot == 0) {
      float lg = s + dn;
      lg = lg > 0.f ? lg : 0.2f * lg;
      float w = expf(lg);
      z = w; acc0 = w * h0; acc1 = w * h1;
    }
  }
  int start = rowptr[n], end = rowptr[n + 1];
  for (int base = start; base < end; base += 64) {
    int m = end - base; if (m > 64) m = 64;
    int idx = (base + lane < end) ? csr[base + lane] : 0;
    int k = slot;
    for (; k + 12 < m; k += 16) {
      int si0 = __shfl(idx, k, 64);
      int si1 = __shfl(idx, k + 4, 64);
      int si2 = __shfl(idx, k + 8, 64);
      int si3 = __shfl(idx, k + 12, 64);
      unsigned u0 = hp[(long long)si0 * 16 + cpair];
      unsigned u1 = hp[(long long)si1 * 16 + cpair];
      unsigned u2 = hp[(long long)si2 * 16 + cpair];
      unsigned u3 = hp[(long long)si3 * 16 + cpair];
      float h00 = h2f((unsigned short)(u0 & 0xffff)), h01 = h2f((unsigned short)(u0 >> 16));
      float h10 = h2f((unsigned short)(u1 & 0xffff)), h11 = h2f((unsigned short)(u1 >> 16));
      float h20 = h2f((unsigned short)(u2 & 0xffff)), h21 = h2f((unsigned short)(u2 >> 16));
      float h30 = h2f((unsigned short)(u3 & 0xffff)), h31 = h2f((unsigned short)(u3 >> 16));
      float s0 = sred(h00 * a0 + h01 * a1);
      float s1 = sred(h10 * a0 + h11 * a1);
      float s2 = sred(h20 * a0 + h21 * a1);
      float s3 = sred(h30 * a0 + h31 * a1);
      float lg0 = s0 + dn; lg0 = lg0 > 0.f ? lg0 : 0.2f * lg0;
      float lg1 = s1 + dn; lg1 = lg1 > 0.f ? lg1 : 0.2f * lg1;
      float lg2 = s2 + dn; lg2 = lg2 > 0.f ? lg2 : 0.2f * lg2;
      float lg3 = s3 + dn; lg3 = lg3 > 0.f ? lg3 : 0.2f * lg3;
      float w0 = expf(lg0), w1 = expf(lg1), w2 = expf(lg2), w3 = expf(lg3);
      z += (w0 + w1) + (w2 + w3);
      acc0 += w0 * h00 + w1 * h10 + w2 * h20 + w3 * h30;
      acc1 += w0 * h01 + w1 * h11 + w2 * h21 + w3 * h31;
    }
    for (; k < m; k += 4) {
      int si0 = __shfl(idx, k, 64);
      unsigned u0 = hp[(long long)si0 * 16 + cpair];
      float h00 = h2f((unsigned short)(u0 & 0xffff)), h01 = h2f((unsigned short)(u0 >> 16));
      float s0 = sred(h00 * a0 + h01 * a1);
      float lg0 = s0 + dn; lg0 = lg0 > 0.f ? lg0 : 0.2f * lg0;
      float w0 = expf(lg0);
      z += w0;
      acc0 += w0 * h00;
      acc1 += w0 * h01;
    }
  }
  acc0 += __shfl_xor(acc0, 16, 64); acc0 += __shfl_xor(acc0, 32, 64);
  acc1 += __shfl_xor(acc1, 16, 64); acc1 += __shfl_xor(acc1, 32, 64);
  z    += __shfl_xor(z, 16, 64);    z    += __shfl_xor(z, 32, 64);
  if (slot == 0) {
    float v0 = acc0 / z + bias[ch];
    float v1 = acc1 / z + bias[ch + 1];
    if (do_elu) {
      v0 = v0 > 0.f ? v0 : (expf(v0) - 1.f);
      v1 = v1 > 0.f ? v1 : (expf(v1) - 1.f);
    }
    *(float2*)&xout[(long long)n * 32 + ch] = make_float2(v0, v1);
  }
}

// ---------------- final fragment-attention pooling ----------------
__global__ __launch_bounds__(256) void pool_kernel(
    const float* __restrict__ x, const float* __restrict__ ys,
    const float* __restrict__ Wfin, const float* __restrict__ bfin,
    float* __restrict__ out, int NB)
{
  __shared__ float ysl[FRAG][CH];
  __shared__ float tl[FRAG];
  int b = blockIdx.y;
  int tid = threadIdx.x;
  for (int idx = tid; idx < FRAG * CH; idx += 256)
    ysl[idx >> 5][idx & 31] = ys[(long long)b * FRAG * CH + idx];
  __syncthreads();
  if (tid < FRAG) {
    float t = 0.f;
    #pragma unroll
    for (int dd = 0; dd < CH; ++dd) t += ysl[tid][dd] * Wfin[dd];
    tl[tid] = t;
  }
  __syncthreads();
  int n = blockIdx.x * 256 + tid;
  if (n >= NB) return;
  const float* xr = x + ((long long)b * NB + n) * CH;
  float xreg[CH];
  #pragma unroll
  for (int dd = 0; dd < CH; ++dd) xreg[dd] = xr[dd];
  float mx = -1e30f;
  for (int f = 0; f < FRAG; ++f) {
    float l = 0.f;
    #pragma unroll
    for (int dd = 0; dd < CH; ++dd) l += xreg[dd] * ysl[f][dd];
    mx = fmaxf(mx, l);
  }
  float se = 0.f, sw = 0.f;
  for (int f = 0; f < FRAG; ++f) {
    float l = 0.f;
    #pragma unroll
    for (int dd = 0; dd < CH; ++dd) l += xreg[dd] * ysl[f][dd];
    float e = expf(l - mx);
    se += e; sw += e * tl[f];
  }
  float logit = sw / se + bfin[0];
  out[(long long)b * NB + n] = 1.f / (1.f + expf(-logit));
}

// ---------------- host orchestration ----------------
extern "C" void kernel_launch(void* const* d_in, const int* in_sizes, int n_in,
                              void* d_out, int out_size, void* d_ws, size_t ws_size,
                              hipStream_t stream)
{
  const float* feats = (const float*)d_in[0];
  const int*   ei    = (const int*)d_in[1];
  const float* frag  = (const float*)d_in[3];
  const float* W1    = (const float*)d_in[4];
  const float* b1    = (const float*)d_in[5];
  const float* W2    = (const float*)d_in[6];
  const float* b2    = (const float*)d_in[7];
  const float* Wc    = (const float*)d_in[8];
  const float* bc    = (const float*)d_in[9];
  const float* g1W   = (const float*)d_in[10];
  const float* g1as  = (const float*)d_in[11];
  const float* g1ad  = (const float*)d_in[12];
  const float* g1b   = (const float*)d_in[13];
  const float* g2W   = (const float*)d_in[14];
  const float* g2as  = (const float*)d_in[15];
  const float* g2ad  = (const float*)d_in[16];
  const float* g2b   = (const float*)d_in[17];
  const float* Wfin  = (const float*)d_in[18];
  const float* bfin  = (const float*)d_in[19];

  const int N  = in_sizes[0] / NF;     // 100000
  const int E  = in_sizes[1] / 2;      // 3200000
  const int BF = in_sizes[3] / NF;     // 400
  const int NB = N / NBATCH;           // 12500

  char* ws = (char*)d_ws;
  size_t off = 0;
  auto walloc = [&](size_t bytes) -> void* {
    void* p = ws + off;
    off += (bytes + 255) & ~(size_t)255;
    return p;
  };
  float*    T1     = (float*)walloc((size_t)M1 * CH * 4);
  float*    Wbig   = (float*)walloc((size_t)NF * CH * 4);
  float*    bfold  = (float*)walloc((size_t)CH * 4);
  float*    x0     = (float*)walloc((size_t)N * CH * 4);
  float*    x1     = (float*)walloc((size_t)N * CH * 4);
  unsigned* hbuf   = (unsigned*)walloc((size_t)N * 16 * 4);    // 64B/node fp16 h
  float*    dbuf   = (float*)walloc((size_t)N * NHEAD1 * 4);
  float*    ysb    = (float*)walloc((size_t)BF * CH * 4);
  int*      degp   = (int*)walloc((size_t)N * DPAD * 4);
  int*      rowptr = (int*)walloc((size_t)(N + 1) * 4);
  int*      rank   = (int*)walloc((size_t)E * 4);
  int*      part   = (int*)walloc((size_t)512 * 4);
  int*      csr    = (int*)walloc((size_t)E * 4);
  (void)ws_size; (void)n_in; (void)out_size;

  // ---- weight folding (tiny): T1 = W2 @ Wc[24:,:]; Wbig[24:,:] = W1 @ T1 ----
  {
    dim3 g1(1, ceil_div(M1, TM));
    gemm_bias<<<g1, 256, 0, stream>>>(W2, M2, Wc + 24 * CH, CH, nullptr, T1, CH,
                                      M1, CH, M2, 0);
    dim3 g2(1, ceil_div(NF - 24, TM));
    gemm_bias<<<g2, 256, 0, stream>>>(W1, M1, T1, CH, nullptr, Wbig + 24 * CH, CH,
                                      NF - 24, CH, M1, 0);
    fold_misc_kernel<<<1, 256, 0, stream>>>(Wc, T1, b1, b2, bc, Wbig, bfold);
  }

  // ---- zero counters; embed GEMM v2 (32-row dbuf) with rank tail; scan; scatter ----
  {
    long long npad = (long long)N * DPAD;
    zero_deg_kernel<<<(int)((npad + 255) / 256), 256, 0, stream>>>(degp, npad);
    int nEmbed = ceil_div(N, 32);            // 3125 blocks
    int chunk = ceil_div(E, nEmbed);         // 1024 edges per block tail
    gemm_n32_rank<<<nEmbed, 256, 0, stream>>>(feats, N, NF, Wbig, bfold, x0,
                                              ei, E, chunk, degp, rank);
    int nb = ceil_div(N, 256);
    partial_kernel<<<nb, 256, 0, stream>>>(degp, N, part);
    scanp_kernel<<<1, 512, 0, stream>>>(part, nb);
    scan_final_kernel<<<nb, 256, 0, stream>>>(degp, N, part, rowptr);
    scatter_plain_kernel<<<ceil_div(E, 256), 256, 0, stream>>>(ei, E, rowptr, rank, csr);
  }

  // ---- fragment embed ----
  gemm_n32<<<ceil_div(BF, 64), 256, 0, stream>>>(frag, BF, NF, Wbig, bfold, ysb);

  // ---- GAT conv helper ----
  auto conv = [&](const float* xin, float* xout, const float* W, const float* as_,
                  const float* ad_, const float* bias, int H, int do_elu) {
    if (H == NHEAD1) {
      proj_sd_kernel<NHEAD1, HID1><<<ceil_div(N, 256), 256, 0, stream>>>(
          xin, W, ad_, hbuf, dbuf, N);
      gat_gather_kernel<NHEAD1, HID1><<<ceil_div(N, 4), 256, 0, stream>>>(
          rowptr, csr, hbuf, as_, dbuf, bias, xout, N, do_elu);
    } else {
      proj_sd_kernel<1, CH><<<ceil_div(N, 256), 256, 0, stream>>>(
          xin, W, ad_, hbuf, dbuf, N);
      gat_gather_kernel<1, CH><<<ceil_div(N, 4), 256, 0, stream>>>(
          rowptr, csr, hbuf, as_, dbuf, bias, xout, N, do_elu);
    }
  };

  for (int l = 0; l < NLAYER; ++l) {
    conv(x0, x1, g1W + l * CH * CH, g1as + l * NHEAD1 * HID1, g1ad + l * NHEAD1 * HID1,
         g1b + l * CH, NHEAD1, 1);
    conv(x1, x0, g2W + l * CH * CH, g2as + l * CH, g2ad + l * CH,
         g2b + l * CH, 1, 0);
  }

  // ---- final pooling ----
  pool_kernel<<<dim3(ceil_div(NB, 256), NBATCH), 256, 0, stream>>>(
      x0, ysb, Wfin, bfin, (float*)d_out, NB);
}